// Round 10
// baseline (564.342 us; speedup 1.0000x reference)
//
#include <hip/hip_runtime.h>
#include <hip/hip_bf16.h>

#define NHID 128
#define NBLK 512     // blocks for coarse hist / partition
#define FCAP 4096    // LDS stash capacity (edges) in fine kernel

typedef __attribute__((ext_vector_type(8))) short short8v;
typedef __attribute__((ext_vector_type(4))) float f32x4;

__device__ __forceinline__ unsigned short f32_to_bf16(float f) {
    unsigned u = __float_as_uint(f);
    u += 0x7fffu + ((u >> 16) & 1u);   // round-to-nearest-even
    return (unsigned short)(u >> 16);
}

// ---------------- two-level CSR build ----------------
// bucket = dst >> 7 (128 nodes per bucket). Packing: src (<=2^17) | dst_low7 << 17.

__global__ __launch_bounds__(256) void coarse_hist_kernel(const int* __restrict__ dst, int E,
                                                          int nbuck, int per,
                                                          int* __restrict__ ghist) {
    __shared__ int h[1024];
    for (int i = threadIdx.x; i < nbuck; i += 256) h[i] = 0;
    __syncthreads();
    int b0 = blockIdx.x * per;
    int b1 = min(E, b0 + per);
    int e = b0 + threadIdx.x * 4;
    for (; e + 4 <= b1; e += 1024) {
        int4 d4 = *reinterpret_cast<const int4*>(&dst[e]);
        atomicAdd(&h[d4.x >> 7], 1);
        atomicAdd(&h[d4.y >> 7], 1);
        atomicAdd(&h[d4.z >> 7], 1);
        atomicAdd(&h[d4.w >> 7], 1);
    }
    for (; e < b1; ++e) atomicAdd(&h[dst[e] >> 7], 1);
    __syncthreads();
    for (int i = threadIdx.x; i < nbuck; i += 256)
        ghist[(size_t)i * NBLK + blockIdx.x] = h[i];
}

// ---- 3-kernel device-wide exclusive scan over counts[n] -> out (+ out[n]=total) ----
__global__ __launch_bounds__(256) void block_sum_kernel(const int* __restrict__ counts, int n,
                                                        int* __restrict__ bsums) {
    __shared__ int red[256];
    int tid = threadIdx.x;
    int base = blockIdx.x * 2048 + tid * 8;
    int s = 0;
#pragma unroll
    for (int i = 0; i < 8; ++i) {
        int idx = base + i;
        if (idx < n) s += counts[idx];
    }
    red[tid] = s;
    __syncthreads();
    for (int off = 128; off > 0; off >>= 1) {
        if (tid < off) red[tid] += red[tid + off];
        __syncthreads();
    }
    if (tid == 0) bsums[blockIdx.x] = red[0];
}

// single block, 256 threads: exclusive scan of bsums[nb] (nb <= 256) -> boffs, boffs[nb]=total
__global__ __launch_bounds__(256) void scan_bsums_kernel(const int* __restrict__ bsums, int nb,
                                                         int* __restrict__ boffs) {
    __shared__ int ws[4];
    int tid = threadIdx.x;
    int lane = tid & 63;
    int wv = tid >> 6;
    int orig = (tid < nb) ? bsums[tid] : 0;
    int v = orig;
#pragma unroll
    for (int off = 1; off < 64; off <<= 1) {
        int u = __shfl_up(v, off, 64);
        if (lane >= off) v += u;
    }
    if (lane == 63) ws[wv] = v;
    __syncthreads();
    int add = 0;
    for (int w = 0; w < wv; ++w) add += ws[w];
    v += add;
    if (tid < nb) boffs[tid] = v - orig;
    if (tid == nb - 1) boffs[nb] = v;
}

__global__ __launch_bounds__(256) void scan_write_kernel(const int* __restrict__ counts, int n,
                                                         const int* __restrict__ boffs, int nb,
                                                         int* __restrict__ out) {
    __shared__ int wsum[4];
    int tid = threadIdx.x;
    int lane = tid & 63;
    int wv = tid >> 6;
    int base = blockIdx.x * 2048 + tid * 8;

    int v[8];
    int s = 0;
#pragma unroll
    for (int i = 0; i < 8; ++i) {
        int idx = base + i;
        v[i] = (idx < n) ? counts[idx] : 0;
        s += v[i];
    }
    int incl = s;
#pragma unroll
    for (int off = 1; off < 64; off <<= 1) {
        int u = __shfl_up(incl, off, 64);
        if (lane >= off) incl += u;
    }
    if (lane == 63) wsum[wv] = incl;
    __syncthreads();
    int wexcl = 0;
    for (int w = 0; w < wv; ++w) wexcl += wsum[w];

    int run = boffs[blockIdx.x] + wexcl + (incl - s);
#pragma unroll
    for (int i = 0; i < 8; ++i) {
        int idx = base + i;
        if (idx < n) out[idx] = run;
        run += v[i];
    }
    if (blockIdx.x == 0 && tid == 0) out[n] = boffs[nb];
}

__global__ __launch_bounds__(256) void partition_kernel(const int* __restrict__ src,
                                                        const int* __restrict__ dst,
                                                        const float* __restrict__ w, int E,
                                                        int nbuck, int per,
                                                        const int* __restrict__ gofs,
                                                        uint2* __restrict__ coarse) {
    __shared__ int cur[1024];
    for (int i = threadIdx.x; i < nbuck; i += 256)
        cur[i] = gofs[(size_t)i * NBLK + blockIdx.x];
    __syncthreads();
    int b0 = blockIdx.x * per;
    int b1 = min(E, b0 + per);
    int e = b0 + threadIdx.x * 4;
    for (; e + 4 <= b1; e += 1024) {
        int4 d4 = *reinterpret_cast<const int4*>(&dst[e]);
        int4 s4 = *reinterpret_cast<const int4*>(&src[e]);
        float4 w4 = *reinterpret_cast<const float4*>(&w[e]);
        int p0 = atomicAdd(&cur[d4.x >> 7], 1);
        int p1 = atomicAdd(&cur[d4.y >> 7], 1);
        int p2 = atomicAdd(&cur[d4.z >> 7], 1);
        int p3 = atomicAdd(&cur[d4.w >> 7], 1);
        coarse[p0] = make_uint2((unsigned)s4.x | ((unsigned)(d4.x & 127) << 17), __float_as_uint(w4.x));
        coarse[p1] = make_uint2((unsigned)s4.y | ((unsigned)(d4.y & 127) << 17), __float_as_uint(w4.y));
        coarse[p2] = make_uint2((unsigned)s4.z | ((unsigned)(d4.z & 127) << 17), __float_as_uint(w4.z));
        coarse[p3] = make_uint2((unsigned)s4.w | ((unsigned)(d4.w & 127) << 17), __float_as_uint(w4.w));
    }
    for (; e < b1; ++e) {
        int d = dst[e];
        int pos = atomicAdd(&cur[d >> 7], 1);
        coarse[pos] = make_uint2((unsigned)src[e] | ((unsigned)(d & 127) << 17),
                                 __float_as_uint(w[e]));
    }
}

// One workgroup per bucket: build exact per-node CSR for its 128 nodes.
// edata[e] = (w_bf15 << 17) | src17  (weight is uniform[0,1): bf16 sign bit = 0).
__global__ __launch_bounds__(256) void fine_kernel(const uint2* __restrict__ coarse,
                                                   const int* __restrict__ gofs, int N, int E,
                                                   int* __restrict__ row_ptr,
                                                   unsigned* __restrict__ edata) {
    __shared__ uint2 stash[FCAP];
    __shared__ int hist[128];
    __shared__ int excl[128];
    int b = blockIdx.x;
    int gstart = gofs[(size_t)b * NBLK];
    int gend = gofs[(size_t)(b + 1) * NBLK];
    int cnt = gend - gstart;
    int tid = threadIdx.x;
    if (tid < 128) hist[tid] = 0;
    __syncthreads();
    for (int i = tid; i < cnt; i += 256) {
        uint2 e = coarse[gstart + i];
        if (i < FCAP) stash[i] = e;
        atomicAdd(&hist[(e.x >> 17) & 127], 1);
    }
    __syncthreads();
    if (tid < 64) {
        int a = hist[tid];
        int c = hist[tid + 64];
        int ia = a, ic = c;
#pragma unroll
        for (int off = 1; off < 64; off <<= 1) {
            int u = __shfl_up(ia, off, 64);
            if (tid >= off) ia += u;
            u = __shfl_up(ic, off, 64);
            if (tid >= off) ic += u;
        }
        int totA = __shfl(ia, 63, 64);
        excl[tid] = ia - a;
        excl[tid + 64] = totA + ic - c;
    }
    __syncthreads();
    int node0 = b << 7;
    if (tid < 128 && node0 + tid < N) row_ptr[node0 + tid] = gstart + excl[tid];
    if (b == 0 && tid == 0) row_ptr[N] = E;
    if (tid < 128) hist[tid] = excl[tid];   // reuse as cursor
    __syncthreads();
    for (int i = tid; i < cnt; i += 256) {
        uint2 e = (i < FCAP) ? stash[i] : coarse[gstart + i];
        int dl = (e.x >> 17) & 127;
        int pos = atomicAdd(&hist[dl], 1);
        unsigned u = e.y;
        unsigned w15 = ((u + 0x7fffu + ((u >> 16) & 1u)) >> 16) & 0x7FFFu;  // bf16 bits, sign=0
        edata[gstart + pos] = (w15 << 17) | (e.x & 0x1FFFFu);
    }
}

// ---------------- converts (slab layout: slab[s][node][16 bf16], s = col/16) ----------------
__global__ void convert_x_slab(const float* __restrict__ x, unsigned short* __restrict__ xb,
                               int n) {
    int total = n * 8;
    int stride = gridDim.x * blockDim.x;
    for (int t = blockIdx.x * blockDim.x + threadIdx.x; t < total; t += stride) {
        int node = t >> 3, sl = t & 7;
        const float4* src = reinterpret_cast<const float4*>(x + (size_t)node * 128 + sl * 16);
        float4 f0 = src[0], f1 = src[1], f2 = src[2], f3 = src[3];
        uint4 o0, o1;
        o0.x = (unsigned)f32_to_bf16(f0.x) | ((unsigned)f32_to_bf16(f0.y) << 16);
        o0.y = (unsigned)f32_to_bf16(f0.z) | ((unsigned)f32_to_bf16(f0.w) << 16);
        o0.z = (unsigned)f32_to_bf16(f1.x) | ((unsigned)f32_to_bf16(f1.y) << 16);
        o0.w = (unsigned)f32_to_bf16(f1.z) | ((unsigned)f32_to_bf16(f1.w) << 16);
        o1.x = (unsigned)f32_to_bf16(f2.x) | ((unsigned)f32_to_bf16(f2.y) << 16);
        o1.y = (unsigned)f32_to_bf16(f2.z) | ((unsigned)f32_to_bf16(f2.w) << 16);
        o1.z = (unsigned)f32_to_bf16(f3.x) | ((unsigned)f32_to_bf16(f3.y) << 16);
        o1.w = (unsigned)f32_to_bf16(f3.z) | ((unsigned)f32_to_bf16(f3.w) << 16);
        unsigned short* dst = xb + (size_t)sl * n * 16 + (size_t)node * 16;
        reinterpret_cast<uint4*>(dst)[0] = o0;
        reinterpret_cast<uint4*>(dst)[1] = o1;
    }
}

// WT[n][k] = bf16(W[k][n]); grid (N/32, K/32), block 256
__global__ __launch_bounds__(256) void transpose_w_bf16(const float* __restrict__ W,
                                                        unsigned short* __restrict__ WT,
                                                        int K, int N) {
    __shared__ float t[32][33];
    int n0 = blockIdx.x * 32, k0 = blockIdx.y * 32;
    int tx = threadIdx.x & 31;
    int ty = threadIdx.x >> 5;  // 0..7
#pragma unroll
    for (int i = 0; i < 32; i += 8)
        t[ty + i][tx] = W[(size_t)(k0 + ty + i) * N + n0 + tx];
    __syncthreads();
#pragma unroll
    for (int i = 0; i < 32; i += 8)
        WT[(size_t)(n0 + ty + i) * K + k0 + tx] = f32_to_bf16(t[tx][ty + i]);
}

// ---------------- SpMM on slabs: out[s][node] = bf16( sum_e w_e * X[s][src_e] ) ----------------
// slice = blockIdx >> 8 (slice-major dispatch -> one 3.2MB slab hot per L2 at a time).
// Per 16-edge VMEM step: lane = (esub 0..15, cq 0..3); each lane loads 8B (4 bf16) of its
// edge's 32B slice -> gathers are L2-resident. Meta (4B/edge) loaded nontemporal.
__global__ __launch_bounds__(256) void spmm_slab_bf16(const unsigned short* __restrict__ Xslab,
                                                      const unsigned* __restrict__ edata,
                                                      const int* __restrict__ row_ptr,
                                                      unsigned short* __restrict__ outSlab,
                                                      int n) {
    const int lane = threadIdx.x & 63;
    const int esub = lane >> 2;    // edge sub-index 0..15
    const int cq = lane & 3;       // 8B chunk of the 32B slice
    const int slice = blockIdx.x >> 8;   // 0..7
    const char* Xb = (const char*)(Xslab + (size_t)slice * n * 16) + cq * 8;
    unsigned short* slabO = outSlab + (size_t)slice * n * 16;
    const int wstart = ((blockIdx.x & 255) << 2) + (threadIdx.x >> 6);

    for (int node = wstart; node < n; node += 1024) {
        int beg = row_ptr[node];
        int end = row_ptr[node + 1];
        float a0 = 0.f, a1 = 0.f, a2 = 0.f, a3 = 0.f;
        for (int e0 = beg; e0 < end; e0 += 64) {
            int cnt = min(64, end - e0);
            unsigned m = 0;
            if (lane < cnt) m = __builtin_nontemporal_load(&edata[e0 + lane]);
            for (int i = 0; i < cnt; i += 16) {
                unsigned mm = (unsigned)__shfl((int)m, i + esub, 64);
                float w = __uint_as_float((mm & 0xFFFE0000u) >> 1);  // bf15 -> f32
                unsigned off = (mm & 0x1FFFFu) << 5;                 // src * 32B
                uint2 v = *reinterpret_cast<const uint2*>(Xb + off);
                a0 += w * __uint_as_float(v.x << 16);
                a1 += w * __uint_as_float(v.x & 0xffff0000u);
                a2 += w * __uint_as_float(v.y << 16);
                a3 += w * __uint_as_float(v.y & 0xffff0000u);
            }
        }
#pragma unroll
        for (int d = 4; d < 64; d <<= 1) {
            a0 += __shfl_xor(a0, d, 64);
            a1 += __shfl_xor(a1, d, 64);
            a2 += __shfl_xor(a2, d, 64);
            a3 += __shfl_xor(a3, d, 64);
        }
        if (lane < 4) {
            uint2 o;
            o.x = (unsigned)f32_to_bf16(a0) | ((unsigned)f32_to_bf16(a1) << 16);
            o.y = (unsigned)f32_to_bf16(a2) | ((unsigned)f32_to_bf16(a3) << 16);
            *reinterpret_cast<uint2*>(slabO + (size_t)node * 16 + lane * 4) = o;
        }
    }
}

// ---------------- MFMA GEMM + bias + ReLU ----------------
// A input (Xb) in slab layout; B (WT) row-major [DOUT][128].
// OUT_BF16: writes slab layout (for next spmm); else f32 row-major.
template <int DOUT, bool OUT_BF16>
__global__ __launch_bounds__(256) void gemm_mfma(const unsigned short* __restrict__ Xb,
                                                 const unsigned short* __restrict__ WT,
                                                 const float* __restrict__ bias,
                                                 void* __restrict__ outv, int nrows) {
    __shared__ unsigned short Ab[128 * 128];
    __shared__ unsigned short Bb[128 * 128];
    const int row0 = blockIdx.x * 128;
    const int col0 = blockIdx.y * 128;
    const int tid = threadIdx.x;
    const int lane = tid & 63;
    const int wid = tid >> 6;
    const int waveM = wid >> 1;
    const int waveN = wid & 1;

    {
        const int c = tid & 15;           // 16B chunk: slab c>>1, half c&1
        int r = tid >> 4;
        const size_t slabStride = (size_t)nrows * 16;
#pragma unroll
        for (int p = 0; p < 8; ++p, r += 16) {
            int row = row0 + r;
            uint4 va = make_uint4(0, 0, 0, 0);
            if (row < nrows)
                va = *reinterpret_cast<const uint4*>(Xb + (size_t)(c >> 1) * slabStride +
                                                     (size_t)row * 16 + (c & 1) * 8);
            uint4 vb = *reinterpret_cast<const uint4*>(&WT[(size_t)(col0 + r) * 128 + c * 8]);
            int cs = (c ^ (r & 15)) * 8;
            *reinterpret_cast<uint4*>(&Ab[r * 128 + cs]) = va;
            *reinterpret_cast<uint4*>(&Bb[r * 128 + cs]) = vb;
        }
    }
    __syncthreads();

    const int lr = lane & 15;
    const int lk = lane >> 4;

    f32x4 acc[4][4];
#pragma unroll
    for (int m = 0; m < 4; ++m)
#pragma unroll
        for (int nn = 0; nn < 4; ++nn) acc[m][nn] = (f32x4){0.f, 0.f, 0.f, 0.f};

#pragma unroll
    for (int ks = 0; ks < 4; ++ks) {
        short8v a[4], b[4];
#pragma unroll
        for (int m = 0; m < 4; ++m) {
            int row = waveM * 64 + m * 16 + lr;
            int c16 = (ks * 4 + lk) ^ (row & 15);
            a[m] = *reinterpret_cast<const short8v*>(&Ab[row * 128 + c16 * 8]);
        }
#pragma unroll
        for (int nn = 0; nn < 4; ++nn) {
            int rowb = waveN * 64 + nn * 16 + lr;
            int c16 = (ks * 4 + lk) ^ (rowb & 15);
            b[nn] = *reinterpret_cast<const short8v*>(&Bb[rowb * 128 + c16 * 8]);
        }
#pragma unroll
        for (int m = 0; m < 4; ++m)
#pragma unroll
            for (int nn = 0; nn < 4; ++nn)
                acc[m][nn] = __builtin_amdgcn_mfma_f32_16x16x32_bf16(a[m], b[nn], acc[m][nn], 0, 0, 0);
    }

    float bj[4];
#pragma unroll
    for (int nn = 0; nn < 4; ++nn) bj[nn] = bias[col0 + waveN * 64 + nn * 16 + lr];

#pragma unroll
    for (int m = 0; m < 4; ++m) {
        int rbase = row0 + waveM * 64 + m * 16 + lk * 4;
#pragma unroll
        for (int reg = 0; reg < 4; ++reg) {
            int r = rbase + reg;
            if (r >= nrows) continue;
#pragma unroll
            for (int nn = 0; nn < 4; ++nn) {
                int cidx = col0 + waveN * 64 + nn * 16 + lr;
                float v = fmaxf(acc[m][nn][reg] + bj[nn], 0.f);
                if (OUT_BF16) {
                    unsigned short* ob = (unsigned short*)outv;
                    ob[(size_t)(cidx >> 4) * nrows * 16 + (size_t)r * 16 + (cidx & 15)] =
                        f32_to_bf16(v);
                } else {
                    ((float*)outv)[(size_t)r * DOUT + cidx] = v;
                }
            }
        }
    }
}

extern "C" void kernel_launch(void* const* d_in, const int* in_sizes, int n_in,
                              void* d_out, int out_size, void* d_ws, size_t ws_size,
                              hipStream_t stream) {
    const float* x  = (const float*)d_in[0];
    const float* ew = (const float*)d_in[1];
    const float* W1 = (const float*)d_in[2];
    const float* b1 = (const float*)d_in[3];
    const float* W2 = (const float*)d_in[4];
    const float* b2 = (const float*)d_in[5];
    const int*   ei = (const int*)d_in[6];

    const int N = in_sizes[0] / NHID;   // 100000 (must be < 131072 for 17-bit src packing)
    const int E = in_sizes[1];          // 1600000
    const int* src = ei;
    const int* dst = ei + E;

    const int nbuck = (N + 127) >> 7;                  // 782
    const int n2 = nbuck * NBLK;                       // 400384 scan elements
    const int nb2 = (n2 + 2047) / 2048;                // 196 (<=256)
    const int per = (((E + NBLK - 1) / NBLK) + 3) & ~3;  // edges per partition block, x4 aligned

    auto align256 = [](size_t v) { return (v + 255) & ~(size_t)255; };
    char* p = (char*)d_ws;
    unsigned short* xb  = (unsigned short*)p; p += align256((size_t)N * NHID * 2);  // slab layout
    unsigned short* gb  = (unsigned short*)p; p += align256((size_t)N * NHID * 2);  // slab layout
    unsigned short* hb  = (unsigned short*)p; p += align256((size_t)N * NHID * 2);  // slab layout
    unsigned short* W1T = (unsigned short*)p; p += align256((size_t)128 * 128 * 2);
    unsigned short* W2T = (unsigned short*)p; p += align256((size_t)256 * 128 * 2);
    int*   ghist   = (int*)p;      p += align256((size_t)(n2 + 1) * 4);
    int*   gofs    = (int*)p;      p += align256((size_t)(n2 + 1) * 4);
    int*   row_ptr = (int*)p;      p += align256((size_t)(N + 1) * 4);
    unsigned* edata = (unsigned*)p; p += align256((size_t)E * 4);
    uint2* coarse  = (uint2*)p;    p += align256((size_t)E * 8);
    int*   bsums   = (int*)p;      p += align256((size_t)256 * 4);
    int*   boffs   = (int*)p;      p += align256((size_t)260 * 4);

    // ---- CSR build: coarse hist -> scan -> partition -> fine ----
    coarse_hist_kernel<<<NBLK, 256, 0, stream>>>(dst, E, nbuck, per, ghist);
    block_sum_kernel<<<nb2, 256, 0, stream>>>(ghist, n2, bsums);
    scan_bsums_kernel<<<1, 256, 0, stream>>>(bsums, nb2, boffs);
    scan_write_kernel<<<nb2, 256, 0, stream>>>(ghist, n2, boffs, nb2, gofs);
    partition_kernel<<<NBLK, 256, 0, stream>>>(src, dst, ew, E, nbuck, per, gofs, coarse);
    fine_kernel<<<nbuck, 256, 0, stream>>>(coarse, gofs, N, E, row_ptr, edata);

    // ---- precision converts ----
    convert_x_slab<<<2048, 256, 0, stream>>>(x, xb, N);
    {
        dim3 g1(128 / 32, 128 / 32);
        transpose_w_bf16<<<g1, 256, 0, stream>>>(W1, W1T, 128, 128);
        dim3 g2(256 / 32, 128 / 32);
        transpose_w_bf16<<<g2, 256, 0, stream>>>(W2, W2T, 128, 256);
    }

    // ---- layer 1: h = relu((A @ x) @ W1 + b1) ----
    spmm_slab_bf16<<<2048, 256, 0, stream>>>(xb, edata, row_ptr, gb, N);
    {
        dim3 grid((N + 127) / 128, 1);
        gemm_mfma<128, true><<<grid, 256, 0, stream>>>(gb, W1T, b1, hb, N);
    }

    // ---- layer 2: out = relu((A @ h) @ W2 + b2) ----
    spmm_slab_bf16<<<2048, 256, 0, stream>>>(hb, edata, row_ptr, gb, N);
    {
        dim3 grid((N + 127) / 128, 2);
        gemm_mfma<256, false><<<grid, 256, 0, stream>>>(gb, W2T, b2, (float*)d_out, N);
    }
}

// Round 11
// 251.645 us; speedup vs baseline: 2.2426x; 2.2426x over previous
//
#include <hip/hip_runtime.h>
#include <hip/hip_bf16.h>

#define NHID 128
#define NBLK 512     // blocks for coarse hist / partition
#define FCAP 4096    // LDS stash capacity (edges) in fine kernel

typedef __attribute__((ext_vector_type(8))) short short8v;
typedef __attribute__((ext_vector_type(4))) float f32x4;

__device__ __forceinline__ unsigned short f32_to_bf16(float f) {
    unsigned u = __float_as_uint(f);
    u += 0x7fffu + ((u >> 16) & 1u);   // round-to-nearest-even
    return (unsigned short)(u >> 16);
}

// ---------------- two-level CSR build ----------------
// bucket = dst >> 7 (128 nodes per bucket). Packing: src (<=2^17) | dst_low7 << 17.

__global__ __launch_bounds__(256) void coarse_hist_kernel(const int* __restrict__ dst, int E,
                                                          int nbuck, int per,
                                                          int* __restrict__ ghist) {
    __shared__ int h[1024];
    for (int i = threadIdx.x; i < nbuck; i += 256) h[i] = 0;
    __syncthreads();
    int b0 = blockIdx.x * per;
    int b1 = min(E, b0 + per);
    int e = b0 + threadIdx.x * 4;
    for (; e + 4 <= b1; e += 1024) {
        int4 d4 = *reinterpret_cast<const int4*>(&dst[e]);
        atomicAdd(&h[d4.x >> 7], 1);
        atomicAdd(&h[d4.y >> 7], 1);
        atomicAdd(&h[d4.z >> 7], 1);
        atomicAdd(&h[d4.w >> 7], 1);
    }
    for (; e < b1; ++e) atomicAdd(&h[dst[e] >> 7], 1);
    __syncthreads();
    for (int i = threadIdx.x; i < nbuck; i += 256)
        ghist[(size_t)i * NBLK + blockIdx.x] = h[i];
}

// ---- 3-kernel device-wide exclusive scan over counts[n] -> out (+ out[n]=total) ----
__global__ __launch_bounds__(256) void block_sum_kernel(const int* __restrict__ counts, int n,
                                                        int* __restrict__ bsums) {
    __shared__ int red[256];
    int tid = threadIdx.x;
    int base = blockIdx.x * 2048 + tid * 8;
    int s = 0;
#pragma unroll
    for (int i = 0; i < 8; ++i) {
        int idx = base + i;
        if (idx < n) s += counts[idx];
    }
    red[tid] = s;
    __syncthreads();
    for (int off = 128; off > 0; off >>= 1) {
        if (tid < off) red[tid] += red[tid + off];
        __syncthreads();
    }
    if (tid == 0) bsums[blockIdx.x] = red[0];
}

// single block, 256 threads: exclusive scan of bsums[nb] (nb <= 256) -> boffs, boffs[nb]=total
__global__ __launch_bounds__(256) void scan_bsums_kernel(const int* __restrict__ bsums, int nb,
                                                         int* __restrict__ boffs) {
    __shared__ int ws[4];
    int tid = threadIdx.x;
    int lane = tid & 63;
    int wv = tid >> 6;
    int orig = (tid < nb) ? bsums[tid] : 0;
    int v = orig;
#pragma unroll
    for (int off = 1; off < 64; off <<= 1) {
        int u = __shfl_up(v, off, 64);
        if (lane >= off) v += u;
    }
    if (lane == 63) ws[wv] = v;
    __syncthreads();
    int add = 0;
    for (int w = 0; w < wv; ++w) add += ws[w];
    v += add;
    if (tid < nb) boffs[tid] = v - orig;
    if (tid == nb - 1) boffs[nb] = v;
}

__global__ __launch_bounds__(256) void scan_write_kernel(const int* __restrict__ counts, int n,
                                                         const int* __restrict__ boffs, int nb,
                                                         int* __restrict__ out) {
    __shared__ int wsum[4];
    int tid = threadIdx.x;
    int lane = tid & 63;
    int wv = tid >> 6;
    int base = blockIdx.x * 2048 + tid * 8;

    int v[8];
    int s = 0;
#pragma unroll
    for (int i = 0; i < 8; ++i) {
        int idx = base + i;
        v[i] = (idx < n) ? counts[idx] : 0;
        s += v[i];
    }
    int incl = s;
#pragma unroll
    for (int off = 1; off < 64; off <<= 1) {
        int u = __shfl_up(incl, off, 64);
        if (lane >= off) incl += u;
    }
    if (lane == 63) wsum[wv] = incl;
    __syncthreads();
    int wexcl = 0;
    for (int w = 0; w < wv; ++w) wexcl += wsum[w];

    int run = boffs[blockIdx.x] + wexcl + (incl - s);
#pragma unroll
    for (int i = 0; i < 8; ++i) {
        int idx = base + i;
        if (idx < n) out[idx] = run;
        run += v[i];
    }
    if (blockIdx.x == 0 && tid == 0) out[n] = boffs[nb];
}

__global__ __launch_bounds__(256) void partition_kernel(const int* __restrict__ src,
                                                        const int* __restrict__ dst,
                                                        const float* __restrict__ w, int E,
                                                        int nbuck, int per,
                                                        const int* __restrict__ gofs,
                                                        uint2* __restrict__ coarse) {
    __shared__ int cur[1024];
    for (int i = threadIdx.x; i < nbuck; i += 256)
        cur[i] = gofs[(size_t)i * NBLK + blockIdx.x];
    __syncthreads();
    int b0 = blockIdx.x * per;
    int b1 = min(E, b0 + per);
    int e = b0 + threadIdx.x * 4;
    for (; e + 4 <= b1; e += 1024) {
        int4 d4 = *reinterpret_cast<const int4*>(&dst[e]);
        int4 s4 = *reinterpret_cast<const int4*>(&src[e]);
        float4 w4 = *reinterpret_cast<const float4*>(&w[e]);
        int p0 = atomicAdd(&cur[d4.x >> 7], 1);
        int p1 = atomicAdd(&cur[d4.y >> 7], 1);
        int p2 = atomicAdd(&cur[d4.z >> 7], 1);
        int p3 = atomicAdd(&cur[d4.w >> 7], 1);
        coarse[p0] = make_uint2((unsigned)s4.x | ((unsigned)(d4.x & 127) << 17), __float_as_uint(w4.x));
        coarse[p1] = make_uint2((unsigned)s4.y | ((unsigned)(d4.y & 127) << 17), __float_as_uint(w4.y));
        coarse[p2] = make_uint2((unsigned)s4.z | ((unsigned)(d4.z & 127) << 17), __float_as_uint(w4.z));
        coarse[p3] = make_uint2((unsigned)s4.w | ((unsigned)(d4.w & 127) << 17), __float_as_uint(w4.w));
    }
    for (; e < b1; ++e) {
        int d = dst[e];
        int pos = atomicAdd(&cur[d >> 7], 1);
        coarse[pos] = make_uint2((unsigned)src[e] | ((unsigned)(d & 127) << 17),
                                 __float_as_uint(w[e]));
    }
}

// One workgroup per bucket: build exact per-node CSR for its 128 nodes.
// src_s stores BYTE offsets (src * 256) for the bf16 gather.
__global__ __launch_bounds__(256) void fine_kernel(const uint2* __restrict__ coarse,
                                                   const int* __restrict__ gofs, int N, int E,
                                                   int* __restrict__ row_ptr,
                                                   int* __restrict__ src_s,
                                                   float* __restrict__ w_s) {
    __shared__ uint2 stash[FCAP];
    __shared__ int hist[128];
    __shared__ int excl[128];
    int b = blockIdx.x;
    int gstart = gofs[(size_t)b * NBLK];
    int gend = gofs[(size_t)(b + 1) * NBLK];
    int cnt = gend - gstart;
    int tid = threadIdx.x;
    if (tid < 128) hist[tid] = 0;
    __syncthreads();
    for (int i = tid; i < cnt; i += 256) {
        uint2 e = coarse[gstart + i];
        if (i < FCAP) stash[i] = e;
        atomicAdd(&hist[(e.x >> 17) & 127], 1);
    }
    __syncthreads();
    if (tid < 64) {
        int a = hist[tid];
        int c = hist[tid + 64];
        int ia = a, ic = c;
#pragma unroll
        for (int off = 1; off < 64; off <<= 1) {
            int u = __shfl_up(ia, off, 64);
            if (tid >= off) ia += u;
            u = __shfl_up(ic, off, 64);
            if (tid >= off) ic += u;
        }
        int totA = __shfl(ia, 63, 64);
        excl[tid] = ia - a;
        excl[tid + 64] = totA + ic - c;
    }
    __syncthreads();
    int node0 = b << 7;
    if (tid < 128 && node0 + tid < N) row_ptr[node0 + tid] = gstart + excl[tid];
    if (b == 0 && tid == 0) row_ptr[N] = E;
    if (tid < 128) hist[tid] = excl[tid];   // reuse as cursor
    __syncthreads();
    for (int i = tid; i < cnt; i += 256) {
        uint2 e = (i < FCAP) ? stash[i] : coarse[gstart + i];
        int dl = (e.x >> 17) & 127;
        int pos = atomicAdd(&hist[dl], 1);
        src_s[gstart + pos] = (int)((e.x & 0x1FFFFu) << 8);   // byte offset into bf16 X
        w_s[gstart + pos] = __uint_as_float(e.y);
    }
}

// ---------------- converts ----------------
__global__ void convert_f32_bf16(const float* __restrict__ x, unsigned short* __restrict__ xb,
                                 size_t n4) {
    size_t stride = (size_t)gridDim.x * blockDim.x;
    for (size_t i = (size_t)blockIdx.x * blockDim.x + threadIdx.x; i < n4; i += stride) {
        float4 v = reinterpret_cast<const float4*>(x)[i];
        ushort4 o = make_ushort4(f32_to_bf16(v.x), f32_to_bf16(v.y), f32_to_bf16(v.z),
                                 f32_to_bf16(v.w));
        reinterpret_cast<ushort4*>(xb)[i] = o;
    }
}

// WT[n][k] = bf16(W[k][n]); grid (N/32, K/32), block 256
__global__ __launch_bounds__(256) void transpose_w_bf16(const float* __restrict__ W,
                                                        unsigned short* __restrict__ WT,
                                                        int K, int N) {
    __shared__ float t[32][33];
    int n0 = blockIdx.x * 32, k0 = blockIdx.y * 32;
    int tx = threadIdx.x & 31;
    int ty = threadIdx.x >> 5;  // 0..7
#pragma unroll
    for (int i = 0; i < 32; i += 8)
        t[ty + i][tx] = W[(size_t)(k0 + ty + i) * N + n0 + tx];
    __syncthreads();
#pragma unroll
    for (int i = 0; i < 32; i += 8)
        WT[(size_t)(n0 + ty + i) * K + k0 + tx] = f32_to_bf16(t[tx][ty + i]);
}

// ---------------- SpMM (bf16 rows): out[node] = bf16( sum_e w_e * X[src_e] ) ----------------
// One wave per node (grid (N+3)/4). Quarter-wave (16 lanes) per gathered row: lane q
// covers cols q*8..q*8+7 (uint4 = 8 bf16). 16 edges per quad-step (4 loads in flight),
// 4/2/1-edge tails. Edge meta loaded NONTEMPORAL (streamed once, keeps X hot in L2).
__global__ __launch_bounds__(256) void spmm_csr_bf16(const unsigned short* __restrict__ X,
                                                     const int* __restrict__ src_s,
                                                     const float* __restrict__ w_s,
                                                     const int* __restrict__ row_ptr,
                                                     unsigned short* __restrict__ out, int n) {
    int node = blockIdx.x * 4 + (threadIdx.x >> 6);
    if (node >= n) return;
    const int lane = threadIdx.x & 63;
    const int grp = lane >> 4;   // 0..3
    const int q = lane & 15;     // 16B chunk
    const char* Xq = (const char*)X + q * 16;

    int beg = row_ptr[node];
    int end = row_ptr[node + 1];

    float acc[8];
#pragma unroll
    for (int j = 0; j < 8; ++j) acc[j] = 0.f;

    for (int e0 = beg; e0 < end; e0 += 64) {
        int cnt = min(64, end - e0);
        int sb = 0;
        float ww = 0.f;
        if (lane < cnt) {
            sb = __builtin_nontemporal_load(&src_s[e0 + lane]);
            ww = __builtin_nontemporal_load(&w_s[e0 + lane]);
        }

        int i = 0;
        for (; i + 16 <= cnt; i += 16) {
            unsigned sx[4];
            float wx[4];
#pragma unroll
            for (int u = 0; u < 4; ++u) {
                sx[u] = (unsigned)__shfl(sb, i + u * 4 + grp, 64);
                wx[u] = __shfl(ww, i + u * 4 + grp, 64);
            }
            uint4 v[4];
#pragma unroll
            for (int u = 0; u < 4; ++u)
                v[u] = *reinterpret_cast<const uint4*>(Xq + sx[u]);
#pragma unroll
            for (int u = 0; u < 4; ++u) {
                unsigned pw;
                pw = v[u].x;
                acc[0] += wx[u] * __uint_as_float(pw << 16);
                acc[1] += wx[u] * __uint_as_float(pw & 0xffff0000u);
                pw = v[u].y;
                acc[2] += wx[u] * __uint_as_float(pw << 16);
                acc[3] += wx[u] * __uint_as_float(pw & 0xffff0000u);
                pw = v[u].z;
                acc[4] += wx[u] * __uint_as_float(pw << 16);
                acc[5] += wx[u] * __uint_as_float(pw & 0xffff0000u);
                pw = v[u].w;
                acc[6] += wx[u] * __uint_as_float(pw << 16);
                acc[7] += wx[u] * __uint_as_float(pw & 0xffff0000u);
            }
        }
        // 4-edge tail
        for (; i + 4 <= cnt; i += 4) {
            unsigned sx = (unsigned)__shfl(sb, i + grp, 64);
            float wx = __shfl(ww, i + grp, 64);
            uint4 v = *reinterpret_cast<const uint4*>(Xq + sx);
            unsigned pw;
            pw = v.x;
            acc[0] += wx * __uint_as_float(pw << 16);
            acc[1] += wx * __uint_as_float(pw & 0xffff0000u);
            pw = v.y;
            acc[2] += wx * __uint_as_float(pw << 16);
            acc[3] += wx * __uint_as_float(pw & 0xffff0000u);
            pw = v.z;
            acc[4] += wx * __uint_as_float(pw << 16);
            acc[5] += wx * __uint_as_float(pw & 0xffff0000u);
            pw = v.w;
            acc[6] += wx * __uint_as_float(pw << 16);
            acc[7] += wx * __uint_as_float(pw & 0xffff0000u);
        }
        // remaining 1..3 edges: quarter-wave grp covers edge i+grp if valid
        if (i < cnt) {
            int idx = i + grp;
            unsigned sx = (unsigned)__shfl(sb, idx, 64);
            float wx = __shfl(ww, idx, 64);
            if (idx < cnt) {
                uint4 v = *reinterpret_cast<const uint4*>(Xq + sx);
                unsigned pw;
                pw = v.x;
                acc[0] += wx * __uint_as_float(pw << 16);
                acc[1] += wx * __uint_as_float(pw & 0xffff0000u);
                pw = v.y;
                acc[2] += wx * __uint_as_float(pw << 16);
                acc[3] += wx * __uint_as_float(pw & 0xffff0000u);
                pw = v.z;
                acc[4] += wx * __uint_as_float(pw << 16);
                acc[5] += wx * __uint_as_float(pw & 0xffff0000u);
                pw = v.w;
                acc[6] += wx * __uint_as_float(pw << 16);
                acc[7] += wx * __uint_as_float(pw & 0xffff0000u);
            }
        }
    }

    // reduce the 4 quarter-wave partial sums
#pragma unroll
    for (int j = 0; j < 8; ++j) {
        acc[j] += __shfl_xor(acc[j], 16, 64);
        acc[j] += __shfl_xor(acc[j], 32, 64);
    }

    if (grp == 0) {
        short8v o;
#pragma unroll
        for (int j = 0; j < 8; ++j) o[j] = (short)f32_to_bf16(acc[j]);
        __builtin_nontemporal_store(o, reinterpret_cast<short8v*>(&out[(size_t)node * NHID + q * 8]));
    }
}

// ---------------- MFMA GEMM + bias + ReLU ----------------
template <int DOUT, bool OUT_BF16>
__global__ __launch_bounds__(256) void gemm_mfma(const unsigned short* __restrict__ Xb,
                                                 const unsigned short* __restrict__ WT,
                                                 const float* __restrict__ bias,
                                                 void* __restrict__ outv, int nrows) {
    __shared__ unsigned short Ab[128 * 128];
    __shared__ unsigned short Bb[128 * 128];
    const int row0 = blockIdx.x * 128;
    const int col0 = blockIdx.y * 128;
    const int tid = threadIdx.x;
    const int lane = tid & 63;
    const int wid = tid >> 6;
    const int waveM = wid >> 1;
    const int waveN = wid & 1;

    {
        const int c = tid & 15;
        int r = tid >> 4;
#pragma unroll
        for (int p = 0; p < 8; ++p, r += 16) {
            int row = row0 + r;
            uint4 va = make_uint4(0, 0, 0, 0);
            if (row < nrows) va = *reinterpret_cast<const uint4*>(&Xb[(size_t)row * 128 + c * 8]);
            uint4 vb = *reinterpret_cast<const uint4*>(&WT[(size_t)(col0 + r) * 128 + c * 8]);
            int cs = (c ^ (r & 15)) * 8;
            *reinterpret_cast<uint4*>(&Ab[r * 128 + cs]) = va;
            *reinterpret_cast<uint4*>(&Bb[r * 128 + cs]) = vb;
        }
    }
    __syncthreads();

    const int lr = lane & 15;
    const int lk = lane >> 4;

    f32x4 acc[4][4];
#pragma unroll
    for (int m = 0; m < 4; ++m)
#pragma unroll
        for (int nn = 0; nn < 4; ++nn) acc[m][nn] = (f32x4){0.f, 0.f, 0.f, 0.f};

#pragma unroll
    for (int ks = 0; ks < 4; ++ks) {
        short8v a[4], b[4];
#pragma unroll
        for (int m = 0; m < 4; ++m) {
            int row = waveM * 64 + m * 16 + lr;
            int c16 = (ks * 4 + lk) ^ (row & 15);
            a[m] = *reinterpret_cast<const short8v*>(&Ab[row * 128 + c16 * 8]);
        }
#pragma unroll
        for (int nn = 0; nn < 4; ++nn) {
            int rowb = waveN * 64 + nn * 16 + lr;
            int c16 = (ks * 4 + lk) ^ (rowb & 15);
            b[nn] = *reinterpret_cast<const short8v*>(&Bb[rowb * 128 + c16 * 8]);
        }
#pragma unroll
        for (int m = 0; m < 4; ++m)
#pragma unroll
            for (int nn = 0; nn < 4; ++nn)
                acc[m][nn] = __builtin_amdgcn_mfma_f32_16x16x32_bf16(a[m], b[nn], acc[m][nn], 0, 0, 0);
    }

    float bj[4];
#pragma unroll
    for (int nn = 0; nn < 4; ++nn) bj[nn] = bias[col0 + waveN * 64 + nn * 16 + lr];

#pragma unroll
    for (int m = 0; m < 4; ++m) {
        int rbase = row0 + waveM * 64 + m * 16 + lk * 4;
#pragma unroll
        for (int reg = 0; reg < 4; ++reg) {
            int r = rbase + reg;
            if (r >= nrows) continue;
#pragma unroll
            for (int nn = 0; nn < 4; ++nn) {
                int cidx = col0 + waveN * 64 + nn * 16 + lr;
                float v = fmaxf(acc[m][nn][reg] + bj[nn], 0.f);
                if (OUT_BF16)
                    ((unsigned short*)outv)[(size_t)r * DOUT + cidx] = f32_to_bf16(v);
                else
                    ((float*)outv)[(size_t)r * DOUT + cidx] = v;
            }
        }
    }
}

extern "C" void kernel_launch(void* const* d_in, const int* in_sizes, int n_in,
                              void* d_out, int out_size, void* d_ws, size_t ws_size,
                              hipStream_t stream) {
    const float* x  = (const float*)d_in[0];
    const float* ew = (const float*)d_in[1];
    const float* W1 = (const float*)d_in[2];
    const float* b1 = (const float*)d_in[3];
    const float* W2 = (const float*)d_in[4];
    const float* b2 = (const float*)d_in[5];
    const int*   ei = (const int*)d_in[6];

    const int N = in_sizes[0] / NHID;   // 100000 (must be < 131072 for 17-bit src packing)
    const int E = in_sizes[1];          // 1600000
    const int* src = ei;
    const int* dst = ei + E;

    const int nbuck = (N + 127) >> 7;                  // 782
    const int n2 = nbuck * NBLK;                       // 400384 scan elements
    const int nb2 = (n2 + 2047) / 2048;                // 196 (<=256)
    const int per = (((E + NBLK - 1) / NBLK) + 3) & ~3;  // edges per partition block, x4 aligned

    auto align256 = [](size_t v) { return (v + 255) & ~(size_t)255; };
    char* p = (char*)d_ws;
    unsigned short* xb  = (unsigned short*)p; p += align256((size_t)N * NHID * 2);
    unsigned short* gb  = (unsigned short*)p; p += align256((size_t)N * NHID * 2);
    unsigned short* hb  = (unsigned short*)p; p += align256((size_t)N * NHID * 2);
    unsigned short* W1T = (unsigned short*)p; p += align256((size_t)128 * 128 * 2);
    unsigned short* W2T = (unsigned short*)p; p += align256((size_t)256 * 128 * 2);
    int*   ghist   = (int*)p;   p += align256((size_t)(n2 + 1) * 4);
    int*   gofs    = (int*)p;   p += align256((size_t)(n2 + 1) * 4);
    int*   row_ptr = (int*)p;   p += align256((size_t)(N + 1) * 4);
    int*   src_s   = (int*)p;   p += align256((size_t)E * 4);
    float* w_s     = (float*)p; p += align256((size_t)E * 4);
    uint2* coarse  = (uint2*)p; p += align256((size_t)E * 8);
    int*   bsums   = (int*)p;   p += align256((size_t)256 * 4);
    int*   boffs   = (int*)p;   p += align256((size_t)260 * 4);

    // ---- CSR build: coarse hist -> scan -> partition -> fine ----
    coarse_hist_kernel<<<NBLK, 256, 0, stream>>>(dst, E, nbuck, per, ghist);
    block_sum_kernel<<<nb2, 256, 0, stream>>>(ghist, n2, bsums);
    scan_bsums_kernel<<<1, 256, 0, stream>>>(bsums, nb2, boffs);
    scan_write_kernel<<<nb2, 256, 0, stream>>>(ghist, n2, boffs, nb2, gofs);
    partition_kernel<<<NBLK, 256, 0, stream>>>(src, dst, ew, E, nbuck, per, gofs, coarse);
    fine_kernel<<<nbuck, 256, 0, stream>>>(coarse, gofs, N, E, row_ptr, src_s, w_s);

    // ---- precision converts ----
    convert_f32_bf16<<<2048, 256, 0, stream>>>(x, xb, (size_t)N * NHID / 4);
    {
        dim3 g1(128 / 32, 128 / 32);
        transpose_w_bf16<<<g1, 256, 0, stream>>>(W1, W1T, 128, 128);
        dim3 g2(256 / 32, 128 / 32);
        transpose_w_bf16<<<g2, 256, 0, stream>>>(W2, W2T, 128, 256);
    }

    // ---- layer 1: h = relu((A @ x) @ W1 + b1) ----
    spmm_csr_bf16<<<(N + 3) / 4, 256, 0, stream>>>(xb, src_s, w_s, row_ptr, gb, N);
    {
        dim3 grid((N + 127) / 128, 1);
        gemm_mfma<128, true><<<grid, 256, 0, stream>>>(gb, W1T, b1, hb, N);
    }

    // ---- layer 2: out = relu((A @ h) @ W2 + b2) ----
    spmm_csr_bf16<<<(N + 3) / 4, 256, 0, stream>>>(hb, src_s, w_s, row_ptr, gb, N);
    {
        dim3 grid((N + 127) / 128, 2);
        gemm_mfma<256, false><<<grid, 256, 0, stream>>>(gb, W2T, b2, (float*)d_out, N);
    }
}